// Round 4
// baseline (389.478 us; speedup 1.0000x reference)
//
#include <hip/hip_runtime.h>

// FloodPath R4: three-kernel pure-stream split.
//   K1 pack:   float2 [H][W][2] -> occ/flood bit planes, COLUMN-major [w][r].
//   K2 flood:  64x224-interior tiles staged coalesced from packed planes,
//              16 bit-parallel dilation steps (2 words/thread in registers,
//              LDS only for vertical exchange), writes 6 packed planes
//              (flood + 5 count bit-slices) column-major, coalesced.
//   K3 expand: pure stream (no LDS, no barriers): planes + flood_count ->
//              float3 output. Structurally identical to fillBuffer (83% BW).
// R3 post-mortem: flood kernel ~120us vs ~48us model - phase-aligned blocks,
// LDS-transpose output chains. Fix: isolate compute, stream the rest.

typedef unsigned long long u64;

#define HH 4096
#define WW 4096
#define WPR 64            // u64 words per image row
#define NSTEPS 16
#define VROWS 224         // interior rows per flood block
#define RROWS 256         // region rows = VROWS + 2*16

// ---------------- K1: bitpack (column-major planes) ----------------
__global__ __launch_bounds__(256) void pack_kernel(
    const float* __restrict__ in, u64* __restrict__ occP, u64* __restrict__ flP)
{
    const int lane = threadIdx.x & 63;
    const int wv   = threadIdx.x >> 6;
    const int r    = blockIdx.x;                  // one image row per block
#pragma unroll
    for (int b = 0; b < 2; ++b) {
        float vx[8], vy[8];
#pragma unroll
        for (int j = 0; j < 8; ++j) {
            const int w = wv * 16 + b * 8 + j;
            const float2 v = *(const float2*)(in + ((size_t)r * WW + (w << 6) + lane) * 2);
            vx[j] = v.x; vy[j] = v.y;
        }
#pragma unroll
        for (int j = 0; j < 8; ++j) {
            const int w = wv * 16 + b * 8 + j;
            const u64 om = __ballot(vx[j] > 0.5f);
            const u64 fm = __ballot(vy[j] > 0.5f);
            if (lane == 0) {
                occP[(size_t)w * HH + r] = om;    // [w][r]
                flP [(size_t)w * HH + r] = fm;
            }
        }
    }
}

// ---------------- K2: flood iterate, packed in / packed out ----------------
__global__ __launch_bounds__(256) void flood_kernel(
    const u64* __restrict__ occP, const u64* __restrict__ flP,
    u64* __restrict__ planes)                     // [6][WPR][HH]
{
    __shared__ u64 bufA[RROWS * 2];
    __shared__ u64 bufB[RROWS * 2];

    const int tid = threadIdx.x;                  // region row
    const int w   = blockIdx.x;                   // interior word column
    const int gr  = blockIdx.y * VROWS + tid - 16;
    const bool rin = (gr >= 0) && (gr < HH);

    // Stage region row: 128 cols = [64w-16, 64w+112), 2 words via funnels.
    u64 oc[3], fl[3];
#pragma unroll
    for (int j = 0; j < 3; ++j) {
        const int q = w - 1 + j;
        const bool v = rin && (q >= 0) && (q < WPR);
        oc[j] = v ? occP[(size_t)q * HH + gr] : ~0ull;  // OOB => wall
        fl[j] = v ? flP [(size_t)q * HH + gr] : 0ull;
    }
    const u64 nocc0 = ~((oc[0] >> 48) | (oc[1] << 16));
    const u64 nocc1 = ~((oc[1] >> 48) | (oc[2] << 16));
    u64 f0 = (fl[0] >> 48) | (fl[1] << 16);
    u64 f1 = (fl[1] >> 48) | (fl[2] << 16);

    u64 c00 = 0, c01 = 0, c02 = 0, c03 = 0, c04 = 0;
    u64 c10 = 0, c11 = 0, c12 = 0, c13 = 0, c14 = 0;

    bufA[tid * 2 + 0] = f0; bufA[tid * 2 + 1] = f1;
    __syncthreads();

    u64* cur = bufA;
    u64* nxt = bufB;
    for (int it = 0; it < NSTEPS; ++it) {
        u64 up0 = 0, up1 = 0, dn0 = 0, dn1 = 0;
        if (tid > 0)         { up0 = cur[(tid - 1) * 2 + 0]; up1 = cur[(tid - 1) * 2 + 1]; }
        if (tid < RROWS - 1) { dn0 = cur[(tid + 1) * 2 + 0]; dn1 = cur[(tid + 1) * 2 + 1]; }
        const u64 nf0 = nocc0 & (f0 | (f0 << 1) | (f0 >> 1) | (f1 << 63) | up0 | dn0);
        const u64 nf1 = nocc1 & (f1 | (f1 << 1) | (f0 >> 63) | (f1 >> 1) | up1 | dn1);
        u64 c, t;
        c = nf0;
        t = c00; c00 = t ^ c; c = t & c;
        t = c01; c01 = t ^ c; c = t & c;
        t = c02; c02 = t ^ c; c = t & c;
        t = c03; c03 = t ^ c; c = t & c;
        c04 ^= c;                                  // max 16: no carry out
        c = nf1;
        t = c10; c10 = t ^ c; c = t & c;
        t = c11; c11 = t ^ c; c = t & c;
        t = c12; c12 = t ^ c; c = t & c;
        t = c13; c13 = t ^ c; c = t & c;
        c14 ^= c;
        nxt[tid * 2 + 0] = nf0; nxt[tid * 2 + 1] = nf1;
        f0 = nf0; f1 = nf1;
        __syncthreads();
        u64* tmp = cur; cur = nxt; nxt = tmp;
    }

    // Interior word = region bits [16,80): coalesced 8B/lane column-major.
    if (tid >= 16 && tid < 16 + VROWS && gr < HH) {
        const size_t o = (size_t)w * HH + gr;
        const size_t P = (size_t)WPR * HH;
        planes[o]         = (f0  >> 16) | (f1  << 48);
        planes[P + o]     = (c00 >> 16) | (c10 << 48);
        planes[2 * P + o] = (c01 >> 16) | (c11 << 48);
        planes[3 * P + o] = (c02 >> 16) | (c12 << 48);
        planes[4 * P + o] = (c03 >> 16) | (c13 << 48);
        planes[5 * P + o] = (c04 >> 16) | (c14 << 48);
    }
}

// ---------------- K3: pure-stream expansion ----------------
__global__ __launch_bounds__(256) void expand_kernel(
    const u64* __restrict__ occP, const u64* __restrict__ planes,
    const float* __restrict__ fcount, float* __restrict__ out)
{
    const int lane = threadIdx.x & 63;
    const int wv   = threadIdx.x >> 6;
    const int w    = blockIdx.x;                  // word column
    const int r0   = blockIdx.y * 64 + wv * 16;   // 16 rows per wave
    const size_t P = (size_t)WPR * HH;
    const size_t col = (size_t)(w << 6) + lane;

#pragma unroll 2
    for (int i = 0; i < 16; ++i) {
        const int r = r0 + i;
        const size_t o = (size_t)w * HH + r;
        const u64 ow = occP[o];
        const u64 fw = planes[o];
        const u64 q0 = planes[P + o];
        const u64 q1 = planes[2 * P + o];
        const u64 q2 = planes[3 * P + o];
        const u64 q3 = planes[4 * P + o];
        const u64 q4 = planes[5 * P + o];
        const float fc = fcount[(size_t)r * WW + col];
        const int cv = (int)((q0 >> lane) & 1ull)
                     + ((int)((q1 >> lane) & 1ull) << 1)
                     + ((int)((q2 >> lane) & 1ull) << 2)
                     + ((int)((q3 >> lane) & 1ull) << 3)
                     + ((int)((q4 >> lane) & 1ull) << 4);
        float3 o3;
        o3.x = (float)((ow >> lane) & 1ull);
        o3.y = (float)((fw >> lane) & 1ull);
        o3.z = (float)cv + fc;
        *(float3*)(out + ((size_t)r * WW + col) * 3) = o3;
    }
}

extern "C" void kernel_launch(void* const* d_in, const int* in_sizes, int n_in,
                              void* d_out, int out_size, void* d_ws, size_t ws_size,
                              hipStream_t stream) {
    const float* flood_input = (const float*)d_in[0];  // [4096][4096][2]
    const float* flood_cnt   = (const float*)d_in[1];  // [4096][4096]
    float* out = (float*)d_out;                        // [4096][4096][3]

    u64* occP   = (u64*)d_ws;                          // 2 MiB
    u64* flP    = occP + (size_t)WPR * HH;             // 2 MiB
    u64* planes = flP  + (size_t)WPR * HH;             // 12 MiB

    pack_kernel<<<dim3(HH), dim3(256), 0, stream>>>(flood_input, occP, flP);
    flood_kernel<<<dim3(WPR, (HH + VROWS - 1) / VROWS), dim3(256), 0, stream>>>(
        occP, flP, planes);
    expand_kernel<<<dim3(WPR, HH / 64), dim3(256), 0, stream>>>(
        occP, planes, flood_cnt, out);
}